// Round 5
// baseline (139.584 us; speedup 1.0000x reference)
//
#include <hip/hip_runtime.h>
#include <stdint.h>

#pragma clang fp contract(off)

typedef unsigned long long ull;

#define HIGHT 0.7f
#define LOWT  0.3f
#define KSEL  128
#define CAP   2048         // candidate buffer per mode (LDS keys in finalize)
#define MAXGT 512
#define TPB   256
#define CHUNK 32           // proposals per fused_iou block (8 threads/proposal)
#define TJ    128          // j-tile for the shared IoU matrix
#define SMP   132          // pitch%32==4: write bank 4pi+q+8s (2-way), read bank 4s+jloc (free)
#define NLAD  7

// counter layout (int cnts[32]):
// [0] posMask  [1] negMask(normal)  [2] notPos
// [3..9] pos ladder  [10..16] neg-normal ladder  [17..23] neg-fallback ladder
__device__ __constant__ float LADV[NLAD] = {0.998f, 0.99f, 0.95f, 0.8f, 0.5f, 0.25f, 0.0625f};

// ---- bit-exact IoU (numpy fp32 op-for-op; no contraction; IEEE div) ----
__device__ __forceinline__ float iou_pair(float ax0, float ay0, float ax1, float ay1, float aarea,
                                          float bx0, float by0, float bx1, float by1, float barea){
#pragma clang fp contract(off)
  float x0 = fmaxf(ax0, bx0);
  float y0 = fmaxf(ay0, by0);
  float x1 = fminf(ax1, bx1);
  float y1 = fminf(ay1, by1);
  float dx = fmaxf(x1 - x0, 0.0f);
  float dy = fmaxf(y1 - y0, 0.0f);
  float inter = dx * dy;
  float uni = (aarea + barea) - inter;
  return inter / uni;   // keep IEEE div: surrogate compares flip near-tie argmax
}

// ---- K1: zero forced/cnts + row max/argmax + LDS-tile col partials + provisional counts ----
__global__ __launch_bounds__(TPB)
void fused_iou(const float4* __restrict__ boxes, const float4* __restrict__ gts,
               int n1, int n2, int nblk,
               float* __restrict__ max_iou, int* __restrict__ input_idx,
               ull* __restrict__ colpart, int* __restrict__ forced,
               int* __restrict__ cnts_part, int* __restrict__ cnts,
               const float* __restrict__ pn, const float* __restrict__ nn)
{
#pragma clang fp contract(off)
  const int b = blockIdx.x, t = threadIdx.x;

  // distributed zeroing (consumed by later kernels; stream order suffices)
  for (int x = b * TPB + t; x < n1; x += nblk * TPB) forced[x] = 0;
  if (b == 0 && t < 32) cnts[t] = 0;

  __shared__ float4 gc[MAXGT];
  __shared__ float  ga[MAXGT];
  __shared__ float  smat[CHUNK * SMP];   // 32 x 132 fp32 = 16.9 KB
  __shared__ float  sm[CHUNK];

  for (int j = t; j < n2; j += TPB){
    float4 g = gts[j];
    float hw = g.z * 0.5f, hh = g.w * 0.5f;
    gc[j] = make_float4(g.x - hw, g.y - hh, g.x + hw, g.y + hh);
    ga[j] = g.z * g.w;
  }
  __syncthreads();

  const int lo = b * CHUNK;
  int cr = n1 - lo; if (cr > CHUNK) cr = CHUNK; if (cr < 0) cr = 0;

  const int pi = t >> 3, q = t & 7;      // 8 threads per proposal
  const bool valid = (pi < cr);
  float px0 = 0, py0 = 0, px1 = 0, py1 = 0, pa = 0;
  if (valid){
    float4 pb = boxes[lo + pi];
    float hw = pb.z * 0.5f, hh = pb.w * 0.5f;
    px0 = pb.x - hw; py0 = pb.y - hh; px1 = pb.x + hw; py1 = pb.y + hh;
    pa = pb.z * pb.w;
  }
  // 4 independent row-argmax chains (disjoint j-sets; merged lexicographically)
  float vA = -1.0f, vB = -1.0f, vC = -1.0f, vD = -1.0f;
  int jA = 0, jB = 0, jC = 0, jD = 0;

  for (int tb = 0; tb < n2; tb += TJ){
    const int tn = min(TJ, n2 - tb);
    // row compute: octant q covers j = tb+q+8s; each IoU stored once in smat.
    // FOUR independent chains overlap the fp32-div latency.
    // smat write bank: (4pi + q + 8s)%32 -> worst 2-way (free).
    if (valid){
      const int jlim = tb + tn;
      int j0 = tb + q;
      for (; j0 + 24 < jlim; j0 += 32){
        const int ja = j0, jb = j0 + 8, jc = j0 + 16, jd = j0 + 24;
        float4 gA = gc[ja]; float aA = ga[ja];
        float4 gB = gc[jb]; float aB = ga[jb];
        float4 gC = gc[jc]; float aC = ga[jc];
        float4 gD = gc[jd]; float aD = ga[jd];
        float u = iou_pair(px0, py0, px1, py1, pa, gA.x, gA.y, gA.z, gA.w, aA);
        float v = iou_pair(px0, py0, px1, py1, pa, gB.x, gB.y, gB.z, gB.w, aB);
        float w = iou_pair(px0, py0, px1, py1, pa, gC.x, gC.y, gC.z, gC.w, aC);
        float x = iou_pair(px0, py0, px1, py1, pa, gD.x, gD.y, gD.z, gD.w, aD);
        smat[pi * SMP + (ja - tb)] = u;
        smat[pi * SMP + (jb - tb)] = v;
        smat[pi * SMP + (jc - tb)] = w;
        smat[pi * SMP + (jd - tb)] = x;
        if (u > vA){ vA = u; jA = ja; }
        if (v > vB){ vB = v; jB = jb; }
        if (w > vC){ vC = w; jC = jc; }
        if (x > vD){ vD = x; jD = jd; }
      }
      for (; j0 < jlim; j0 += 8){
        float4 g0 = gc[j0]; float a0 = ga[j0];
        float u = iou_pair(px0, py0, px1, py1, pa, g0.x, g0.y, g0.z, g0.w, a0);
        smat[pi * SMP + (j0 - tb)] = u;
        if (u > vA){ vA = u; jA = j0; }
      }
    }
    __syncthreads();
    // col reduce: 2 threads/j, blocked p-chains of 16 (disjoint ascending ->
    // merge lower-p on tie = global first occurrence). Read bank:
    // (4s + jloc)%32 across a wave -> conflict-free. Row-major colpart write
    // is coalesced (4KB/block contiguous).
    {
      const int jloc = t >> 1, half = t & 1;
      if (jloc < tn){
        float cv = -1.0f; int cp = 0;
        const int p0 = half * 16;
        const int p1 = min(p0 + 16, cr);
        for (int p = p0; p < p1; ++p){
          float v = smat[p * SMP + jloc];
          if (v > cv){ cv = v; cp = p; }
        }
        float ov = __shfl_xor(cv, 1, 64);
        int   op = __shfl_xor(cp, 1, 64);
        if (ov > cv || (ov == cv && op < cp)){ cv = ov; cp = op; }
        if (half == 0){
          // key: bits(nonneg IoU)<<32 | ~globalIdx -> max = best val, tie lowest idx
          colpart[(size_t)b * n2 + (tb + jloc)] =
            ((ull)__float_as_uint(cv) << 32) | (ull)(unsigned)~(unsigned)(lo + cp);
        }
      }
    }
    __syncthreads();
  }

  // merge the 4 chains (disjoint j-sets -> lexicographic merge is exact)
  if (vB > vA || (vB == vA && jB < jA)){ vA = vB; jA = jB; }
  if (vC > vA || (vC == vA && jC < jA)){ vA = vC; jA = jC; }
  if (vD > vA || (vD == vA && jD < jA)){ vA = vD; jA = jD; }
  // merge the 8 octants of the row argmax (tie -> lower j)
  #pragma unroll
  for (int m = 1; m <= 4; m <<= 1){
    float ov = __shfl_xor(vA, m, 64);
    int   oj = __shfl_xor(jA, m, 64);
    if (ov > vA || (ov == vA && oj < jA)){ vA = ov; jA = oj; }
  }
  if (valid && q == 0){
    max_iou[lo + pi] = vA;
    input_idx[lo + pi] = jA;
    sm[pi] = vA;
  }
  __syncthreads();

  // provisional counts (ignore forced; colfix3 corrects): wave 0, lane t = proposal
  if (t < 64){
    const bool vld = (t < cr);
    float m = vld ? sm[t] : -1.0f;
    bool pos = vld && (m > HIGHT);
    bool nm  = vld && (m < LOWT);
    bool np  = vld && !(m > HIGHT);
    float sp = pos ? pn[lo + t] : -1.0f;
    float sn = (nm || np) ? nn[lo + t] : -1.0f;
    int c[24];
    c[0] = __popcll(__ballot(pos));
    c[1] = __popcll(__ballot(nm));
    c[2] = __popcll(__ballot(np));
    #pragma unroll
    for (int k = 0; k < NLAD; ++k){
      float L = LADV[k];
      c[3 + k]  = __popcll(__ballot(pos && sp > L));
      c[10 + k] = __popcll(__ballot(nm  && sn > L));
      c[17 + k] = __popcll(__ballot(np  && sn > L));
    }
    if (t == 0){
      #pragma unroll
      for (int k = 0; k < 24; ++k) cnts_part[b * 24 + k] = c[k];
    }
  }
}

// ---- K2: column-sliced full reduction + inline forcefix + cnts reduce.
// Block b owns 8 columns; reduces them over ALL nblk rows (each block-row
// read = one whole 64B line), then applies the forced-scatter corrections
// for its own columns. Exact; no fences (kernel boundary syncs with K3).
__global__ __launch_bounds__(512)
void colfix3(const ull* __restrict__ colpart, int n1, int n2, int nblk,
             const float* __restrict__ max_iou,
             const float* __restrict__ pn, const float* __restrict__ nn,
             int* __restrict__ forced, const int* __restrict__ cnts_part,
             int* __restrict__ cnts)
{
  const int t = threadIdx.x, b = blockIdx.x, nb = gridDim.x;
  const int c = b * 8 + (t & 7);        // column owned by this thread
  const int s = t >> 3;                 // row stripe 0..63
  ull m = 0;
  if (c < n2){
    for (int r = s; r < nblk; r += 64){
      ull v = colpart[(size_t)r * n2 + c];
      if (v > m) m = v;
    }
  }
  __shared__ ull cm[8][64];
  cm[t & 7][s] = m;

  // provisional counter reduction (strided across blocks; exact after kernel)
  int csum = 0;
  if (t < 24){
    for (int x = b; x < nblk; x += nb) csum += cnts_part[x * 24 + t];
  }
  __syncthreads();
  if (t < 24 && csum) atomicAdd(&cnts[t], csum);

  if (t < 8){
    const int cc = b * 8 + t;
    if (cc < n2){
      ull best = 0;
      for (int k = 0; k < 64; ++k){ ull v = cm[t][k]; if (v > best) best = v; }
      unsigned idx = ~(unsigned)(best & 0xFFFFFFFFull);
      if (idx < (unsigned)n1){
        int old = atomicExch(&forced[idx], 1);    // dedupe: first claimer corrects
        if (old == 0){
          float m2 = max_iou[idx];
          if (!(m2 > HIGHT)){                     // forcing flips this row to pos
            float sp = pn[idx];
            float sn = nn[idx];
            atomicAdd(&cnts[0], 1);
            atomicAdd(&cnts[2], -1);
            #pragma unroll
            for (int k = 0; k < NLAD; ++k){
              float L = LADV[k];
              if (sp > L) atomicAdd(&cnts[3 + k], 1);
              if (sn > L) atomicAdd(&cnts[17 + k], -1);
            }
            if (m2 < LOWT){
              atomicAdd(&cnts[1], -1);
              #pragma unroll
              for (int k = 0; k < NLAD; ++k)
                if (sn > LADV[k]) atomicAdd(&cnts[10 + k], -1);
            }
          }
        }
      }
    }
  }
}

// ---- tau: LARGEST ladder level with >= KSEL survivors (tight superset).
// Exact: the top-KSEL by noise are strictly above that level; if no level
// qualifies (totM < KSEL, or adversarial flat ladder) tau=-1 collects all
// masked (fill path handles totM < KSEL identically to before).
__device__ __forceinline__ float pick_tau2(const int* lad){
  for (int k = 0; k < NLAD; ++k)
    if (lad[k] >= KSEL) return LADV[k];
  return -1.0f;
}

// ---- K3: per-mode collect (vectorized scan into LDS) + exact rank-select.
// Block 0 = pos mode, block 1 = neg mode. Collect and select share the block,
// so only __syncthreads separates them (no global cand round-trip).
__global__ __launch_bounds__(1024)
void finalize(const float* __restrict__ max_iou, const int* __restrict__ forced,
              const float* __restrict__ pn, const float* __restrict__ nn,
              const int* __restrict__ cnts, const int* __restrict__ input_idx,
              int n1, int* __restrict__ out)
{
  const int t = threadIdx.x;
  const bool isPos = (blockIdx.x == 0);
  __shared__ int s_c[24];
  __shared__ int lcnt;
  __shared__ ull keys[CAP];
  if (t < 24) s_c[t] = cnts[t];
  if (t == 0) lcnt = 0;
  __syncthreads();
  const bool fb = (s_c[1] == 0);                 // no negatives -> complement of pos
  const int totM = isPos ? s_c[0] : (fb ? s_c[2] : s_c[1]);
  const float tau = isPos ? pick_tau2(&s_c[3]) : pick_tau2(fb ? &s_c[17] : &s_c[10]);
  const float* noise = isPos ? pn : nn;
  const bool fillOn = (totM < KSEL);

  // Key: (bits(score)+1)<<32 | ~i (score in [0,1) -> bits monotone; +1 so the
  // fill key (k32=0) loses to a real 0.0 score; ~i -> ties pick lowest index,
  // and fill keys order by ascending index, matching ref top_k).
  const int n4 = n1 >> 2;
  for (int v = t; v < n4; v += 1024){
    const float4 m4 = reinterpret_cast<const float4*>(max_iou)[v];
    const int4  f4 = reinterpret_cast<const int4*>(forced)[v];
    const float4 s4 = reinterpret_cast<const float4*>(noise)[v];
    #pragma unroll
    for (int e = 0; e < 4; ++e){
      const float m  = (e==0)?m4.x:(e==1)?m4.y:(e==2)?m4.z:m4.w;
      const int   f  = (e==0)?f4.x:(e==1)?f4.y:(e==2)?f4.z:f4.w;
      const float sc = (e==0)?s4.x:(e==1)?s4.y:(e==2)?s4.z:s4.w;
      const int i = v * 4 + e;
      const bool pos = (m > HIGHT) || (f != 0);
      const bool sel = isPos ? pos : (fb ? (!pos) : ((m < LOWT) && f == 0));
      if (sel){
        if (sc > tau){
          int p = atomicAdd(&lcnt, 1);
          if (p < CAP) keys[p] = ((ull)(__float_as_uint(sc) + 1u) << 32) | (ull)(unsigned)~(unsigned)i;
        }
      } else if (fillOn && i < 2 * KSEL){
        int p = atomicAdd(&lcnt, 1);
        if (p < CAP) keys[p] = (ull)(unsigned)~(unsigned)i;
      }
    }
  }
  for (int i = (n4 << 2) + t; i < n1; i += 1024){
    const float m = max_iou[i];
    const int   f = forced[i];
    const float sc = noise[i];
    const bool pos = (m > HIGHT) || (f != 0);
    const bool sel = isPos ? pos : (fb ? (!pos) : ((m < LOWT) && f == 0));
    if (sel){
      if (sc > tau){
        int p = atomicAdd(&lcnt, 1);
        if (p < CAP) keys[p] = ((ull)(__float_as_uint(sc) + 1u) << 32) | (ull)(unsigned)~(unsigned)i;
      }
    } else if (fillOn && i < 2 * KSEL){
      int p = atomicAdd(&lcnt, 1);
      if (p < CAP) keys[p] = (ull)(unsigned)~(unsigned)i;
    }
  }
  __syncthreads();

  // exact rank-select of top-KSEL (keys totally ordered, unique)
  int n = lcnt; if (n > CAP) n = CAP;
  ull mk[2]; int mr[2];
  #pragma unroll
  for (int e = 0; e < 2; ++e){
    int x = t + e * 1024;
    mk[e] = (x < n) ? keys[x] : ~0ull;   // sentinel outranks everything -> never written
    mr[e] = 0;
  }
  for (int o = 0; o < n; ++o){
    ull ko = keys[o];                    // uniform addr -> LDS broadcast
    mr[0] += (ko > mk[0]);
    mr[1] += (ko > mk[1]);
  }
  #pragma unroll
  for (int e = 0; e < 2; ++e){
    int x = t + e * 1024;
    if (x < n && mr[e] < KSEL){
      unsigned idx = ~(unsigned)(mk[e] & 0xFFFFFFFFull);
      if (isPos){ out[mr[e]] = (int)idx; out[KSEL + mr[e]] = input_idx[idx]; }
      else        out[2 * KSEL + mr[e]] = (int)idx;
    }
  }
}

extern "C" void kernel_launch(void* const* d_in, const int* in_sizes, int n_in,
                              void* d_out, int out_size, void* d_ws, size_t ws_size,
                              hipStream_t stream){
  const float4* boxes = (const float4*)d_in[0];
  const float4* gts   = (const float4*)d_in[1];
  const float* pos_noise = (const float*)d_in[2];
  const float* neg_noise = (const float*)d_in[3];
  const int n1 = in_sizes[0] / 4;
  const int n2 = in_sizes[1] / 4;
  int* out = (int*)d_out;

  char* ws = (char*)d_ws;
  size_t off = 0;
  auto carve = [&](size_t bytes) -> char* {
    char* p = ws + off;
    off = (off + bytes + 255) & ~(size_t)255;
    return p;
  };
  const int nblk = (n1 + CHUNK - 1) / CHUNK;       // 1563
  float* max_iou   = (float*)carve((size_t)n1 * 4);
  int*   input_idx = (int*)  carve((size_t)n1 * 4);
  ull*   colpart   = (ull*)  carve((size_t)nblk * n2 * 8);
  int*   forced    = (int*)  carve((size_t)n1 * 4);
  int*   cnts_part = (int*)  carve((size_t)nblk * 24 * 4);
  int*   cnts      = (int*)  carve(32 * 4);

  fused_iou<<<nblk, TPB, 0, stream>>>(boxes, gts, n1, n2, nblk,
                                      max_iou, input_idx, colpart, forced,
                                      cnts_part, cnts, pos_noise, neg_noise);
  const int cb = (n2 + 7) / 8;                     // 64 blocks: 8 columns each
  colfix3<<<cb, 512, 0, stream>>>(colpart, n1, n2, nblk, max_iou,
                                  pos_noise, neg_noise, forced, cnts_part, cnts);
  finalize<<<2, 1024, 0, stream>>>(max_iou, forced, pos_noise, neg_noise,
                                   cnts, input_idx, n1, out);
}

// Round 7
// 130.659 us; speedup vs baseline: 1.0683x; 1.0683x over previous
//
#include <hip/hip_runtime.h>
#include <stdint.h>

#pragma clang fp contract(off)

typedef unsigned long long ull;

#define HIGHT 0.7f
#define LOWT  0.3f
#define KSEL  128
#define CAP   2048         // candidate buffer per mode
#define MAXGT 512
#define TPB   256
#define TPW   512          // fused_iou block size (16 threads/proposal -> 32 waves/CU)
#define CHUNK 32           // proposals per fused_iou block
#define TJ    128          // j-tile for the shared IoU matrix
#define SMP   132          // pitch%32==4: read bank 4p+jloc conflict-free (proven col phase)
#define NLAD  7
#define NRB   96           // colreduce2 blocks (96 atomics/colmax address, fire-and-forget)

// counter layout (int cnts[32]):
// [0] posMask  [1] negMask(normal)  [2] notPos
// [3..9] pos ladder  [10..16] neg-normal ladder  [17..23] neg-fallback ladder
// [24] collect cnt pos  [25] collect cnt neg
__device__ __constant__ float LADV[NLAD] = {0.998f, 0.99f, 0.95f, 0.8f, 0.5f, 0.25f, 0.0625f};

// ---- bit-exact IoU (numpy fp32 op-for-op; no contraction; IEEE div) ----
__device__ __forceinline__ float iou_pair(float ax0, float ay0, float ax1, float ay1, float aarea,
                                          float bx0, float by0, float bx1, float by1, float barea){
#pragma clang fp contract(off)
  float x0 = fmaxf(ax0, bx0);
  float y0 = fmaxf(ay0, by0);
  float x1 = fminf(ax1, bx1);
  float y1 = fminf(ay1, by1);
  float dx = fmaxf(x1 - x0, 0.0f);
  float dy = fmaxf(y1 - y0, 0.0f);
  float inter = dx * dy;
  float uni = (aarea + barea) - inter;
  return inter / uni;   // keep IEEE div: surrogate compares flip near-tie argmax
}

// ---- K1: 512 threads (16/proposal). Zero forced/cnts/colmax + row max/argmax +
// LDS-tile col partials + provisional counts. LDS 27KB, 40 VGPR -> 4 blocks x
// 8 waves = 32 waves/CU (HW cap) vs 256-thread version's LDS-capped 20.
__global__ __launch_bounds__(TPW)
void fused_iou(const float4* __restrict__ boxes, const float4* __restrict__ gts,
               int n1, int n2, int nblk,
               float* __restrict__ max_iou, int* __restrict__ input_idx,
               ull* __restrict__ colpart, int* __restrict__ forced,
               int* __restrict__ cnts_part, int* __restrict__ cnts,
               ull* __restrict__ colmax,
               const float* __restrict__ pn, const float* __restrict__ nn)
{
#pragma clang fp contract(off)
  const int b = blockIdx.x, t = threadIdx.x;

  // distributed zeroing (consumed by later kernels; stream order suffices).
  // NOTE: colmax MUST be zeroed here — the harness re-poisons the workspace
  // between runs, and colreduce2 atomicMax's into it (R6 failure: this line
  // was dropped and poison keys won the max).
  for (int x = b * TPW + t; x < n1; x += nblk * TPW) forced[x] = 0;
  if (b == 0){
    if (t < 32) cnts[t] = 0;
    for (int x = t; x < n2; x += TPW) colmax[x] = 0;  // key 0 loses to any real key
  }

  __shared__ float4 gc[MAXGT];
  __shared__ float  ga[MAXGT];
  __shared__ float  smat[CHUNK * SMP];   // 32 x 132 fp32 = 16.9 KB
  __shared__ float  sm[CHUNK];

  for (int j = t; j < n2; j += TPW){
    float4 g = gts[j];
    float hw = g.z * 0.5f, hh = g.w * 0.5f;
    gc[j] = make_float4(g.x - hw, g.y - hh, g.x + hw, g.y + hh);
    ga[j] = g.z * g.w;
  }
  __syncthreads();

  const int lo = b * CHUNK;
  int cr = n1 - lo; if (cr > CHUNK) cr = CHUNK; if (cr < 0) cr = 0;

  const int pi = t >> 4, q = t & 15;     // 16 threads per proposal (never straddles a wave)
  const bool valid = (pi < cr);
  float px0 = 0, py0 = 0, px1 = 0, py1 = 0, pa = 0;
  if (valid){
    float4 pb = boxes[lo + pi];
    float hw = pb.z * 0.5f, hh = pb.w * 0.5f;
    px0 = pb.x - hw; py0 = pb.y - hh; px1 = pb.x + hw; py1 = pb.y + hh;
    pa = pb.z * pb.w;
  }
  // 4 independent row-argmax chains (disjoint j-sets; merged lexicographically)
  float vA = -1.0f, vB = -1.0f, vC = -1.0f, vD = -1.0f;
  int jA = 0, jB = 0, jC = 0, jD = 0;

  for (int tb = 0; tb < n2; tb += TJ){
    const int tn = min(TJ, n2 - tb);
    // row compute: thread q covers j = tb+q+16s; each IoU stored once in smat.
    // FOUR independent chains (j0,+16,+32,+48) overlap the fp32-div latency.
    if (valid){
      const int jlim = tb + tn;
      int j0 = tb + q;
      for (; j0 + 48 < jlim; j0 += 64){
        const int ja = j0, jb = j0 + 16, jc = j0 + 32, jd = j0 + 48;
        float4 gA = gc[ja]; float aA = ga[ja];
        float4 gB = gc[jb]; float aB = ga[jb];
        float4 gC = gc[jc]; float aC = ga[jc];
        float4 gD = gc[jd]; float aD = ga[jd];
        float u = iou_pair(px0, py0, px1, py1, pa, gA.x, gA.y, gA.z, gA.w, aA);
        float v = iou_pair(px0, py0, px1, py1, pa, gB.x, gB.y, gB.z, gB.w, aB);
        float w = iou_pair(px0, py0, px1, py1, pa, gC.x, gC.y, gC.z, gC.w, aC);
        float x = iou_pair(px0, py0, px1, py1, pa, gD.x, gD.y, gD.z, gD.w, aD);
        smat[pi * SMP + (ja - tb)] = u;
        smat[pi * SMP + (jb - tb)] = v;
        smat[pi * SMP + (jc - tb)] = w;
        smat[pi * SMP + (jd - tb)] = x;
        if (u > vA){ vA = u; jA = ja; }
        if (v > vB){ vB = v; jB = jb; }
        if (w > vC){ vC = w; jC = jc; }
        if (x > vD){ vD = x; jD = jd; }
      }
      for (; j0 < jlim; j0 += 16){
        float4 g0 = gc[j0]; float a0 = ga[j0];
        float u = iou_pair(px0, py0, px1, py1, pa, g0.x, g0.y, g0.z, g0.w, a0);
        smat[pi * SMP + (j0 - tb)] = u;
        if (u > vA){ vA = u; jA = j0; }
      }
    }
    __syncthreads();
    // col reduce: EXACT R4 pattern (proven conflict-free): threads t<256,
    // 2 threads/j, blocked p-chains of 16 (disjoint ascending -> merge
    // lower-p on tie = global first occurrence). Threads >=256 wait at the
    // barrier (phase is short). Row-major colpart write coalesced.
    if (t < 256){
      const int jloc = t >> 1, half = t & 1;
      if (jloc < tn){
        float cv = -1.0f; int cp = 0;
        const int p0 = half * 16;
        const int p1 = min(p0 + 16, cr);
        for (int p = p0; p < p1; ++p){
          float v = smat[p * SMP + jloc];
          if (v > cv){ cv = v; cp = p; }
        }
        float ov = __shfl_xor(cv, 1, 64);
        int   op = __shfl_xor(cp, 1, 64);
        if (ov > cv || (ov == cv && op < cp)){ cv = ov; cp = op; }
        if (half == 0){
          // key: bits(nonneg IoU)<<32 | ~globalIdx -> max = best val, tie lowest idx
          colpart[(size_t)b * n2 + (tb + jloc)] =
            ((ull)__float_as_uint(cv) << 32) | (ull)(unsigned)~(unsigned)(lo + cp);
        }
      }
    }
    __syncthreads();
  }

  // merge the 4 chains (disjoint j-sets -> lexicographic merge is exact)
  if (vB > vA || (vB == vA && jB < jA)){ vA = vB; jA = jB; }
  if (vC > vA || (vC == vA && jC < jA)){ vA = vC; jA = jC; }
  if (vD > vA || (vD == vA && jD < jA)){ vA = vD; jA = jD; }
  // merge the 16 lanes of the proposal group (tie -> lower j)
  #pragma unroll
  for (int m = 1; m <= 8; m <<= 1){
    float ov = __shfl_xor(vA, m, 64);
    int   oj = __shfl_xor(jA, m, 64);
    if (ov > vA || (ov == vA && oj < jA)){ vA = ov; jA = oj; }
  }
  if (valid && q == 0){
    max_iou[lo + pi] = vA;
    input_idx[lo + pi] = jA;
    sm[pi] = vA;
  }
  __syncthreads();

  // provisional counts (ignore forced; forcefix corrects): wave 0, lane t = proposal
  if (t < 64){
    const bool vld = (t < cr);
    float m = vld ? sm[t] : -1.0f;
    bool pos = vld && (m > HIGHT);
    bool nm  = vld && (m < LOWT);
    bool np  = vld && !(m > HIGHT);
    float sp = pos ? pn[lo + t] : -1.0f;
    float sn = (nm || np) ? nn[lo + t] : -1.0f;
    int c[24];
    c[0] = __popcll(__ballot(pos));
    c[1] = __popcll(__ballot(nm));
    c[2] = __popcll(__ballot(np));
    #pragma unroll
    for (int k = 0; k < NLAD; ++k){
      float L = LADV[k];
      c[3 + k]  = __popcll(__ballot(pos && sp > L));
      c[10 + k] = __popcll(__ballot(nm  && sn > L));
      c[17 + k] = __popcll(__ballot(np  && sn > L));
    }
    if (t == 0){
      #pragma unroll
      for (int k = 0; k < 24; ++k) cnts_part[b * 24 + k] = c[k];
    }
  }
}

// ---- K2: fence-free row-sliced column reduction (coalesced) + cnts reduce.
// Thread t owns columns t and t+256; each block scans rows b, b+NRB, ...
// reading full 4KB rows coalesced. One fire-and-forget atomicMax per column
// per block (NRB per address, issued at block end, no barrier behind them).
__global__ __launch_bounds__(TPB)
void colreduce2(const ull* __restrict__ colpart, int n2, int nblk,
                const int* __restrict__ cnts_part,
                int* __restrict__ cnts, ull* __restrict__ colmax)
{
  const int t = threadIdx.x, b = blockIdx.x;
  ull m0 = 0, m1 = 0;
  const int c0 = t, c1 = t + TPB;          // n2 = 512 = 2*TPB
  for (int x = b; x < nblk; x += NRB){
    const ull* row = colpart + (size_t)x * n2;
    ull v0 = row[c0];
    ull v1 = (c1 < n2) ? row[c1] : 0;
    if (v0 > m0) m0 = v0;
    if (v1 > m1) m1 = v1;
  }
  if (c0 < n2 && m0) atomicMax(&colmax[c0], m0);
  if (c1 < n2 && m1) atomicMax(&colmax[c1], m1);

  // provisional counter reduction (24 columns)
  if (t < 24){
    int s = 0;
    for (int x = b; x < nblk; x += NRB) s += cnts_part[x * 24 + t];
    if (s) atomicAdd(&cnts[t], s);
  }
}

// ---- K3: forced scatter + exact counter corrections (1 block, <=512 threads).
// Visibility of colmax/cnts guaranteed by the kernel boundary (no fences).
__global__ __launch_bounds__(512)
void forcefix(const ull* __restrict__ colmax, int n1, int n2,
              const float* __restrict__ max_iou,
              const float* __restrict__ pn, const float* __restrict__ nn,
              int* __restrict__ forced, int* __restrict__ cnts)
{
  const int t = threadIdx.x;
  if (t >= n2) return;
  ull key = colmax[t];
  unsigned idx = ~(unsigned)(key & 0xFFFFFFFFull);
  if (idx >= (unsigned)n1) return;
  int old = atomicExch(&forced[idx], 1);      // dedupe: first claimer corrects
  if (old != 0) return;
  float m2 = max_iou[idx];
  if (m2 > HIGHT) return;                     // forcing flips this row to pos
  float sp = pn[idx];
  float sn = nn[idx];
  atomicAdd(&cnts[0], 1);
  atomicAdd(&cnts[2], -1);
  #pragma unroll
  for (int k = 0; k < NLAD; ++k){
    float L = LADV[k];
    if (sp > L) atomicAdd(&cnts[3 + k], 1);
    if (sn > L) atomicAdd(&cnts[17 + k], -1);
  }
  if (m2 < LOWT){
    atomicAdd(&cnts[1], -1);
    #pragma unroll
    for (int k = 0; k < NLAD; ++k)
      if (sn > LADV[k]) atomicAdd(&cnts[10 + k], -1);
  }
}

// ---- tau: LARGEST ladder level with >= KSEL survivors (tight superset).
// Exact: the top-KSEL by noise all have score > that level; if no level
// qualifies (implies totM < KSEL whp) tau=-1 collects all masked.
__device__ __forceinline__ float pick_tau2(const int* lad){
  for (int k = 0; k < NLAD; ++k)
    if (lad[k] >= KSEL) return LADV[k];
  return -1.0f;
}

// ---- K4: grid-wide collect into global cand buffers ----
__global__ __launch_bounds__(TPB)
void collect_kernel(const float* __restrict__ max_iou, const int* __restrict__ forced,
                    const float* __restrict__ pn, const float* __restrict__ nn,
                    int n1, int* __restrict__ cnts, ull* __restrict__ cand)
{
  __shared__ int s_c[24];
  const int t = threadIdx.x;
  if (t < 24) s_c[t] = cnts[t];
  __syncthreads();
  const bool fb = (s_c[1] == 0);                 // no negatives -> complement of pos
  const int totP = s_c[0];
  const int totN = fb ? s_c[2] : s_c[1];
  const float tauP = pick_tau2(&s_c[3]);
  const float tauN = pick_tau2(fb ? &s_c[17] : &s_c[10]);

  const int i = blockIdx.x * TPB + t;
  if (i >= n1) return;
  float m = max_iou[i];
  bool f = forced[i] != 0;
  bool pos = (m > HIGHT) || f;
  // Key: (bits(score)+1)<<32 | ~i (score in [0,1) -> bits monotone; +1 so the
  // fill key (k32=0) loses to a real 0.0 score).
  if (pos){
    float sc = pn[i];
    if (sc > tauP){
      int p = atomicAdd(&cnts[24], 1);
      if (p < CAP) cand[p] = ((ull)(__float_as_uint(sc) + 1u) << 32) | (ull)(unsigned)~(unsigned)i;
    }
  } else if (totP < KSEL && i < 2 * KSEL){
    // ref top_k fills with -1-scored entries in ascending index; all needed
    // fills have index < 2*KSEL
    int p = atomicAdd(&cnts[24], 1);
    if (p < CAP) cand[p] = (ull)(unsigned)~(unsigned)i;
  }
  bool seln = fb ? (!pos) : ((m < LOWT) && !f);
  if (seln){
    float sc = nn[i];
    if (sc > tauN){
      int p = atomicAdd(&cnts[25], 1);
      if (p < CAP) cand[CAP + p] = ((ull)(__float_as_uint(sc) + 1u) << 32) | (ull)(unsigned)~(unsigned)i;
    }
  } else if (totN < KSEL && i < 2 * KSEL){
    int p = atomicAdd(&cnts[25], 1);
    if (p < CAP) cand[CAP + p] = (ull)(unsigned)~(unsigned)i;
  }
}

// ---- K5: exact rank-select of top-128 per mode (keys totally ordered, unique) ----
__global__ __launch_bounds__(1024)
void select_kernel(const ull* __restrict__ cand, const int* __restrict__ cnts,
                   const int* __restrict__ input_idx, int* __restrict__ out)
{
  const int t = threadIdx.x;
  const bool isPos = (blockIdx.x == 0);
  __shared__ ull keys[CAP];
  int n = cnts[isPos ? 24 : 25]; if (n > CAP) n = CAP;
  for (int x = t; x < n; x += 1024)
    keys[x] = cand[(isPos ? 0 : CAP) + x];
  __syncthreads();
  // fixed register slots (compile-time indices); sentinel ~0ull never selected
  ull mk[2]; int mr[2];
  #pragma unroll
  for (int e = 0; e < 2; ++e){
    int x = t + e * 1024;
    mk[e] = (x < n) ? keys[x] : ~0ull;
    mr[e] = 0;
  }
  for (int o = 0; o < n; ++o){
    ull ko = keys[o];                             // uniform addr -> LDS broadcast
    #pragma unroll
    for (int e = 0; e < 2; ++e) mr[e] += (ko > mk[e]);
  }
  #pragma unroll
  for (int e = 0; e < 2; ++e){
    int x = t + e * 1024;
    if (x < n && mr[e] < KSEL){
      unsigned idx = ~(unsigned)(mk[e] & 0xFFFFFFFFull);
      if (isPos){ out[mr[e]] = (int)idx; out[KSEL + mr[e]] = input_idx[idx]; }
      else        out[2 * KSEL + mr[e]] = (int)idx;
    }
  }
}

extern "C" void kernel_launch(void* const* d_in, const int* in_sizes, int n_in,
                              void* d_out, int out_size, void* d_ws, size_t ws_size,
                              hipStream_t stream){
  const float4* boxes = (const float4*)d_in[0];
  const float4* gts   = (const float4*)d_in[1];
  const float* pos_noise = (const float*)d_in[2];
  const float* neg_noise = (const float*)d_in[3];
  const int n1 = in_sizes[0] / 4;
  const int n2 = in_sizes[1] / 4;
  int* out = (int*)d_out;

  char* ws = (char*)d_ws;
  size_t off = 0;
  auto carve = [&](size_t bytes) -> char* {
    char* p = ws + off;
    off = (off + bytes + 255) & ~(size_t)255;
    return p;
  };
  const int nblk = (n1 + CHUNK - 1) / CHUNK;       // 1563
  float* max_iou   = (float*)carve((size_t)n1 * 4);
  int*   input_idx = (int*)  carve((size_t)n1 * 4);
  ull*   colpart   = (ull*)  carve((size_t)nblk * n2 * 8);
  int*   forced    = (int*)  carve((size_t)n1 * 4);
  int*   cnts_part = (int*)  carve((size_t)nblk * 24 * 4);
  int*   cnts      = (int*)  carve(32 * 4);
  ull*   colmax    = (ull*)  carve((size_t)MAXGT * 8);
  ull*   cand      = (ull*)  carve((size_t)2 * CAP * 8);

  const int gb = (n1 + TPB - 1) / TPB;             // 196
  fused_iou<<<nblk, TPW, 0, stream>>>(boxes, gts, n1, n2, nblk,
                                      max_iou, input_idx, colpart, forced,
                                      cnts_part, cnts, colmax, pos_noise, neg_noise);
  colreduce2<<<NRB, TPB, 0, stream>>>(colpart, n2, nblk, cnts_part, cnts, colmax);
  forcefix<<<1, 512, 0, stream>>>(colmax, n1, n2, max_iou,
                                  pos_noise, neg_noise, forced, cnts);
  collect_kernel<<<gb, TPB, 0, stream>>>(max_iou, forced, pos_noise, neg_noise,
                                         n1, cnts, cand);
  select_kernel<<<2, 1024, 0, stream>>>(cand, cnts, input_idx, out);
}